// Round 5
// baseline (1402.083 us; speedup 1.0000x reference)
//
#include <hip/hip_runtime.h>
#include <cmath>

// ---------------------------------------------------------------------------
// ClassifierGNN: N=768 nodes, D=128 feat, edge-MLP channels 256->128->1,
// node-MLP 256->130->65.
// Heavy part: per-pair edge MLP over 768^2 pairs with global BatchNorm.
// 3 recompute phases (stats0, stats1, sim) using bf16 MFMA 16x16x32.
// R4 -> R5: fit the 128-VGPR budget BY CONSTRUCTION.
//   Evidence R1-R4: allocator pins 128 VGPRs for 512-thr blocks regardless of
//   LDS/attributes; scratch spill (1.09 GB writes) also capped occupancy at
//   23%. Fix: tile 8x16 -> 8x8 pairs. acc0 64->32 regs, acc1 32->16; peak
//   live ~100 < 128. LDS arena 34.8KB (feat 8K + X 16K, a0 32K overlaid).
// ---------------------------------------------------------------------------

#define N_NODES 768
#define NBJ 96          // j-tiles per row of tiles (768/8)
#define NTILES 9216     // (768/8) * (768/8)

// LDS layout (bytes): arena[0,32768) holds {feat,X} then a0 (overlaid).
#define L_FEAT 0        // 16 rows * 128 f32 = 8192
#define L_X    8192     // 64 q * 128 c * bf16 = 16384 (dies after layer0)
#define L_A0   0        // 64 q * 256 c * bf16 = 32768 (overlays feat+X)
#define L_SB   32768    // 512 f32 = 2048 (stat/sim staging)
#define L_TOT  34816

typedef __bf16 bf16x8_t __attribute__((ext_vector_type(8)));
typedef float f32x4_t __attribute__((ext_vector_type(4)));
typedef unsigned short u16x8_t __attribute__((ext_vector_type(8)));
typedef unsigned short u16x4_t __attribute__((ext_vector_type(4)));

__device__ __forceinline__ unsigned short f2bf(float f) {
  unsigned int u = __float_as_uint(f);
  u += 0x7fffu + ((u >> 16) & 1u);          // round-to-nearest-even
  return (unsigned short)(u >> 16);
}

// ---------------------------------------------------------------------------
// Weight pre-cast: f32 -> bf16, same row-major layout (fragment-ready).
// ---------------------------------------------------------------------------
__global__ void wcast_kernel(const float* __restrict__ w0, const float* __restrict__ w1,
                             unsigned short* __restrict__ w0b, unsigned short* __restrict__ w1b)
{
  const int i = (int)(blockIdx.x * 256 + threadIdx.x);
  if (i < 32768) { w0b[i] = f2bf(w0[i]); w1b[i] = f2bf(w1[i]); }
}

// ---------------------------------------------------------------------------
// Fused pair-MLP kernel.
// Tile = 8 i-rows x 8 j-cols = 64 pairs. 512 threads = 8 waves.
// Waves: aog = wid>>1 (layer0: 64 o's / layer1: 32 p's), bqg = wid&1 (32 q's).
// PHASE 1: z0 -> per-channel sum/sumsq (atomics)
// PHASE 2: z0 -> a0 -> z1 -> sum/sumsq
// PHASE 3: z0 -> a0 -> z1 -> a1 -> sim = sigmoid(wout.a1 + bout)
// A-fragments (weights) loaded per-ks from bf16 global (L2-resident).
// ---------------------------------------------------------------------------
template<int PHASE>
__global__ void
__attribute__((amdgpu_flat_work_group_size(512, 512), amdgpu_waves_per_eu(4, 4)))
pair_phase_kernel(const float* __restrict__ feat,
                  const unsigned short* __restrict__ W0b,
                  const unsigned short* __restrict__ W1b,
                  const float* __restrict__ wout,
                  const float* __restrict__ boutp,
                  const float* __restrict__ sc0, const float* __restrict__ sh0,
                  const float* __restrict__ sc1, const float* __restrict__ sh1,
                  float* __restrict__ stats,
                  float* __restrict__ sim)
{
  __shared__ __align__(16) unsigned char smem[L_TOT];
  float* featL = (float*)(smem + L_FEAT);
  unsigned char* Xb = smem + L_X;
  unsigned char* Ab = smem + L_A0;
  float* sb = (float*)(smem + L_SB);

  const int tid = (int)threadIdx.x;
  const int wid = tid >> 6;
  const int lane = tid & 63;
  const int lr = lane & 15;
  const int g = lane >> 4;
  const int aog = wid >> 1;   // 0..3
  const int bqg = wid & 1;    // 0..1

  // per-wave weight base pointers (element offsets; +ot*2048 / +pt*4096 later)
  const unsigned short* W0base = W0b + (aog * 64 + lr) * 128 + g * 8;
  const unsigned short* W1base = W1b + (aog * 32 + lr) * 256 + g * 8;

  float s1[4][4], s2v[4][4];   // phase1 accumulators (z0)
  float t1[2][4], t2v[2][4];   // phase2 accumulators (z1)
  if constexpr (PHASE == 1) {
#pragma unroll
    for (int ot = 0; ot < 4; ++ot)
#pragma unroll
      for (int r2 = 0; r2 < 4; ++r2) { s1[ot][r2] = 0.f; s2v[ot][r2] = 0.f; }
  }
  if constexpr (PHASE == 2) {
#pragma unroll
    for (int pt = 0; pt < 2; ++pt)
#pragma unroll
      for (int r2 = 0; r2 < 4; ++r2) { t1[pt][r2] = 0.f; t2v[pt][r2] = 0.f; }
  }

  for (int tile = (int)blockIdx.x; tile < NTILES; tile += (int)gridDim.x) {
    const int ti = tile / NBJ;
    const int i0 = ti * 8;
    const int j0 = (tile - ti * NBJ) * 8;
    __syncthreads();   // prev tile's arena reads done before overwrite

    // stage 16 feat rows (8 i-rows, 8 j-rows) -> LDS (512 f32x4 items)
    {
      const int rrow = tid >> 5;
      const int c4 = (tid & 31) * 4;
      const int grow = (rrow < 8) ? (i0 + rrow) : (j0 + rrow - 8);
      *(f32x4_t*)(featL + rrow * 128 + c4) = *(const f32x4_t*)(feat + grow * 128 + c4);
    }
    __syncthreads();

    // generate X[q][c] = |f_i[c] - f_j[c]| as bf16, XOR-swizzled rows
    // 64 q * 16 c-groups = 1024 items; 2 iters/thread
#pragma unroll
    for (int it = 0; it < 2; ++it) {
      const int id = tid + it * 512;
      const int q = id >> 4;
      const int c0 = (id & 15) * 8;
      const float* fi = featL + (q >> 3) * 128 + c0;
      const float* fj = featL + (8 + (q & 7)) * 128 + c0;
      u16x8_t xv;
#pragma unroll
      for (int s = 0; s < 8; ++s) xv[s] = f2bf(fabsf(fi[s] - fj[s]));
      const int off = ((q << 8) + (c0 << 1)) ^ ((q & 7) << 4);
      *(u16x8_t*)(Xb + off) = xv;
    }
    __syncthreads();

    // ---- layer 0: z0[o][q] = W0 . X  (o: 4 tiles/wave, q: 2 tiles/wave) ----
    f32x4_t acc0[4][2];
#pragma unroll
    for (int ot = 0; ot < 4; ++ot)
#pragma unroll
      for (int qt = 0; qt < 2; ++qt)
        acc0[ot][qt] = f32x4_t{0.f, 0.f, 0.f, 0.f};
#pragma unroll
    for (int ks = 0; ks < 4; ++ks) {
      bf16x8_t Af[4];
#pragma unroll
      for (int ot = 0; ot < 4; ++ot)
        Af[ot] = *(const bf16x8_t*)(W0base + ot * 2048 + ks * 32);
      bf16x8_t Bf[2];
#pragma unroll
      for (int qt = 0; qt < 2; ++qt) {
        const int q = bqg * 32 + qt * 16 + lr;
        const int off = ((q << 8) + (ks << 6) + (g << 4)) ^ ((q & 7) << 4);
        Bf[qt] = *(const bf16x8_t*)(Xb + off);
      }
      __builtin_amdgcn_sched_barrier(0);   // cap operand window to this iter
#pragma unroll
      for (int ot = 0; ot < 4; ++ot)
#pragma unroll
        for (int qt = 0; qt < 2; ++qt)
          acc0[ot][qt] = __builtin_amdgcn_mfma_f32_16x16x32_bf16(Af[ot], Bf[qt], acc0[ot][qt], 0, 0, 0);
      __builtin_amdgcn_sched_barrier(0);
    }

    if constexpr (PHASE == 1) {
#pragma unroll
      for (int ot = 0; ot < 4; ++ot)
#pragma unroll
        for (int qt = 0; qt < 2; ++qt)
#pragma unroll
          for (int r2 = 0; r2 < 4; ++r2) {
            const float z = acc0[ot][qt][r2];
            s1[ot][r2] += z;
            s2v[ot][r2] += z * z;
          }
    } else {
      __syncthreads();   // all waves done reading X before a0 overlays arena

      // a0 = lrelu(scale0*z0 + shift0), write bf16 into swizzled LDS [q][o]
#pragma unroll
      for (int ot = 0; ot < 4; ++ot) {
        const int o0 = aog * 64 + ot * 16 + g * 4;
        const f32x4_t scv = *(const f32x4_t*)(sc0 + o0);
        const f32x4_t shv = *(const f32x4_t*)(sh0 + o0);
#pragma unroll
        for (int qt = 0; qt < 2; ++qt) {
          const int q = bqg * 32 + qt * 16 + lr;
          u16x4_t pk;
#pragma unroll
          for (int r2 = 0; r2 < 4; ++r2) {
            float v = acc0[ot][qt][r2] * scv[r2] + shv[r2];
            v = (v >= 0.f) ? v : 0.01f * v;
            pk[r2] = f2bf(v);
          }
          const int off = ((q << 9) + (o0 << 1)) ^ ((q & 7) << 4);
          *(u16x4_t*)(Ab + off) = pk;
        }
      }
      __syncthreads();

      // ---- layer 1: z1[p][q] = W1 . a0 ----
      f32x4_t acc1[2][2];
#pragma unroll
      for (int pt = 0; pt < 2; ++pt)
#pragma unroll
        for (int qt = 0; qt < 2; ++qt)
          acc1[pt][qt] = f32x4_t{0.f, 0.f, 0.f, 0.f};
#pragma unroll
      for (int ks = 0; ks < 8; ++ks) {
        bf16x8_t Af1[2];
#pragma unroll
        for (int pt = 0; pt < 2; ++pt)
          Af1[pt] = *(const bf16x8_t*)(W1base + pt * 4096 + ks * 32);
        bf16x8_t Bf[2];
#pragma unroll
        for (int qt = 0; qt < 2; ++qt) {
          const int q = bqg * 32 + qt * 16 + lr;
          const int off = ((q << 9) + (ks << 6) + (g << 4)) ^ ((q & 7) << 4);
          Bf[qt] = *(const bf16x8_t*)(Ab + off);
        }
        __builtin_amdgcn_sched_barrier(0);
#pragma unroll
        for (int pt = 0; pt < 2; ++pt)
#pragma unroll
          for (int qt = 0; qt < 2; ++qt)
            acc1[pt][qt] = __builtin_amdgcn_mfma_f32_16x16x32_bf16(Af1[pt], Bf[qt], acc1[pt][qt], 0, 0, 0);
        __builtin_amdgcn_sched_barrier(0);
      }

      if constexpr (PHASE == 2) {
#pragma unroll
        for (int pt = 0; pt < 2; ++pt)
#pragma unroll
          for (int qt = 0; qt < 2; ++qt)
#pragma unroll
            for (int r2 = 0; r2 < 4; ++r2) {
              const float z = acc1[pt][qt][r2];
              t1[pt][r2] += z;
              t2v[pt][r2] += z * z;
            }
      } else {
        // PHASE 3: a1 = lrelu(scale1*z1+shift1); sim = sigmoid(wout.a1+bout)
        float part[2] = {0.f, 0.f};
#pragma unroll
        for (int pt = 0; pt < 2; ++pt) {
          const int p0 = aog * 32 + pt * 16 + g * 4;
          const f32x4_t scv = *(const f32x4_t*)(sc1 + p0);
          const f32x4_t shv = *(const f32x4_t*)(sh1 + p0);
          const f32x4_t wv = *(const f32x4_t*)(wout + p0);
#pragma unroll
          for (int qt = 0; qt < 2; ++qt)
#pragma unroll
            for (int r2 = 0; r2 < 4; ++r2) {
              float v = acc1[pt][qt][r2] * scv[r2] + shv[r2];
              v = (v >= 0.f) ? v : 0.01f * v;
              part[qt] += wv[r2] * v;
            }
        }
#pragma unroll
        for (int qt = 0; qt < 2; ++qt) {   // reduce over g (p sub-slots)
          part[qt] += __shfl_xor(part[qt], 16, 64);
          part[qt] += __shfl_xor(part[qt], 32, 64);
        }
        if (lane < 16) {
#pragma unroll
          for (int qt = 0; qt < 2; ++qt)
            sb[aog * 64 + bqg * 32 + qt * 16 + lr] = part[qt];
        }
        __syncthreads();
        if (tid < 64) {
          const float sv = sb[tid] + sb[64 + tid] + sb[128 + tid] + sb[192 + tid] + boutp[0];
          const float sg = 1.f / (1.f + expf(-sv));
          sim[(i0 + (tid >> 3)) * N_NODES + j0 + (tid & 7)] = sg;
        }
      }
    }
  }

  // ---- stats flush: shuffle-reduce over the 16 q-lanes, combine the two
  //      q-group waves in LDS, then one atomicAdd per stat per block. ----
  if constexpr (PHASE == 1) {
#pragma unroll
    for (int ot = 0; ot < 4; ++ot)
#pragma unroll
      for (int r2 = 0; r2 < 4; ++r2) {
        float v1 = s1[ot][r2], v2 = s2v[ot][r2];
#pragma unroll
        for (int m = 1; m < 16; m <<= 1) {
          v1 += __shfl_xor(v1, m, 64);
          v2 += __shfl_xor(v2, m, 64);
        }
        s1[ot][r2] = v1; s2v[ot][r2] = v2;
      }
    __syncthreads();
    if (bqg == 0 && lr == 0) {
#pragma unroll
      for (int ot = 0; ot < 4; ++ot)
#pragma unroll
        for (int r2 = 0; r2 < 4; ++r2) {
          const int o = aog * 64 + ot * 16 + g * 4 + r2;
          sb[o] = s1[ot][r2];
          sb[256 + o] = s2v[ot][r2];
        }
    }
    __syncthreads();
    if (bqg == 1 && lr == 0) {
#pragma unroll
      for (int ot = 0; ot < 4; ++ot)
#pragma unroll
        for (int r2 = 0; r2 < 4; ++r2) {
          const int o = aog * 64 + ot * 16 + g * 4 + r2;
          sb[o] += s1[ot][r2];
          sb[256 + o] += s2v[ot][r2];
        }
    }
    __syncthreads();
    atomicAdd(stats + tid, sb[tid]);   // tid < 512: 256 sums + 256 sumsq
  }
  if constexpr (PHASE == 2) {
#pragma unroll
    for (int pt = 0; pt < 2; ++pt)
#pragma unroll
      for (int r2 = 0; r2 < 4; ++r2) {
        float v1 = t1[pt][r2], v2 = t2v[pt][r2];
#pragma unroll
        for (int m = 1; m < 16; m <<= 1) {
          v1 += __shfl_xor(v1, m, 64);
          v2 += __shfl_xor(v2, m, 64);
        }
        t1[pt][r2] = v1; t2v[pt][r2] = v2;
      }
    __syncthreads();
    if (bqg == 0 && lr == 0) {
#pragma unroll
      for (int pt = 0; pt < 2; ++pt)
#pragma unroll
        for (int r2 = 0; r2 < 4; ++r2) {
          const int p = aog * 32 + pt * 16 + g * 4 + r2;
          sb[p] = t1[pt][r2];
          sb[128 + p] = t2v[pt][r2];
        }
    }
    __syncthreads();
    if (bqg == 1 && lr == 0) {
#pragma unroll
      for (int pt = 0; pt < 2; ++pt)
#pragma unroll
        for (int r2 = 0; r2 < 4; ++r2) {
          const int p = aog * 32 + pt * 16 + g * 4 + r2;
          sb[p] += t1[pt][r2];
          sb[128 + p] += t2v[pt][r2];
        }
    }
    __syncthreads();
    if (tid < 256) atomicAdd(stats + tid, sb[tid]);
  }
}

// ---------------------------------------------------------------------------
// finalize: mean/var -> per-channel scale/shift for BN(+gamma,beta)
// ---------------------------------------------------------------------------
__global__ void finalize_kernel(const float* __restrict__ ssum, const float* __restrict__ ssq,
                                const float* __restrict__ gamma, const float* __restrict__ beta,
                                float* __restrict__ sc, float* __restrict__ sh, int n)
{
  const int i = (int)(blockIdx.x * blockDim.x + threadIdx.x);
  if (i < n) {
    const float invN = 1.f / 589824.f;
    const float m = ssum[i] * invN;
    const float var = ssq[i] * invN - m * m;
    const float is = rsqrtf(var + 1e-5f);
    const float s = gamma[i] * is;
    sc[i] = s;
    sh[i] = beta[i] - m * s;
  }
}

// ---------------------------------------------------------------------------
// edge graph tail: colsum of edge matrix (edge = same_label*sim + I + 1e-6)
// ---------------------------------------------------------------------------
__global__ void colsum_kernel(const float* __restrict__ sim, const int* __restrict__ lab,
                              float* __restrict__ colsum)
{
  const int t = (int)threadIdx.x;
  const int bi = (int)blockIdx.x * 8;
  const int lj0 = lab[t], lj1 = lab[t + 256], lj2 = lab[t + 512];
  float a0 = 0.f, a1 = 0.f, a2 = 0.f;
  for (int r = 0; r < 8; ++r) {
    const int i = bi + r;
    const int li = lab[i];
    const float* srow = sim + i * N_NODES;
    a0 += ((li == lj0) ? srow[t] : 0.f) + ((i == t) ? 1.f : 0.f) + 1e-6f;
    a1 += ((li == lj1) ? srow[t + 256] : 0.f) + ((i == t + 256) ? 1.f : 0.f) + 1e-6f;
    a2 += ((li == lj2) ? srow[t + 512] : 0.f) + ((i == t + 512) ? 1.f : 0.f) + 1e-6f;
  }
  atomicAdd(colsum + t, a0);
  atomicAdd(colsum + t + 256, a1);
  atomicAdd(colsum + t + 512, a2);
}

// aggr[i][:] = (e_row_i / max(sum|e_row_i|,1e-12)) @ feat,  e = colnorm(edge) with zero diag
__global__ void aggr_kernel(const float* __restrict__ sim, const int* __restrict__ lab,
                            const float* __restrict__ colsum, const float* __restrict__ feat,
                            float* __restrict__ aggr)
{
  __shared__ float wrow[N_NODES];
  __shared__ float red[128];
  const int i = (int)blockIdx.x, t = (int)threadIdx.x;
  const int li = lab[i];
  const float* srow = sim + i * N_NODES;
  float rs = 0.f;
  for (int s = 0; s < 6; ++s) {
    const int j = t + s * 128;
    const float e = ((li == lab[j]) ? srow[j] : 0.f) + ((i == j) ? 1.f : 0.f) + 1e-6f;
    const float w = (j == i) ? 0.f : e / colsum[j];
    wrow[j] = w;
    rs += w;
  }
  red[t] = rs;
  __syncthreads();
  for (int off = 64; off > 0; off >>= 1) {
    if (t < off) red[t] += red[t + off];
    __syncthreads();
  }
  const float inv = 1.f / fmaxf(red[0], 1e-12f);
  float acc = 0.f;
  for (int j = 0; j < N_NODES; ++j) acc += wrow[j] * feat[j * 128 + t];
  aggr[i * 128 + t] = acc * inv;
}

// node MLP layer0: h2[r][n] = lrelu(bn(n_w0 @ [feat;aggr]^T)), bn over n
__global__ void mlp0_kernel(const float* __restrict__ feat, const float* __restrict__ aggr,
                            const float* __restrict__ w, const float* __restrict__ gamma,
                            const float* __restrict__ beta, float* __restrict__ h2)
{
  __shared__ float wr[256];
  __shared__ float redA[256], redB[256];
  const int r = (int)blockIdx.x, t = (int)threadIdx.x;
  wr[t] = w[r * 256 + t];
  __syncthreads();
  float v[3];
#pragma unroll
  for (int s = 0; s < 3; ++s) {
    const int n = t + s * 256;
    const float* fr = feat + n * 128;
    const float* ar = aggr + n * 128;
    float acc = 0.f;
#pragma unroll 4
    for (int c = 0; c < 128; c += 4) {
      const f32x4_t fv = *(const f32x4_t*)(fr + c);
      acc += wr[c] * fv[0] + wr[c + 1] * fv[1] + wr[c + 2] * fv[2] + wr[c + 3] * fv[3];
    }
#pragma unroll 4
    for (int c = 0; c < 128; c += 4) {
      const f32x4_t av = *(const f32x4_t*)(ar + c);
      acc += wr[128 + c] * av[0] + wr[129 + c] * av[1] + wr[130 + c] * av[2] + wr[131 + c] * av[3];
    }
    v[s] = acc;
  }
  redA[t] = v[0] + v[1] + v[2];
  redB[t] = v[0] * v[0] + v[1] * v[1] + v[2] * v[2];
  __syncthreads();
  for (int off = 128; off > 0; off >>= 1) {
    if (t < off) { redA[t] += redA[t + off]; redB[t] += redB[t + off]; }
    __syncthreads();
  }
  const float m = redA[0] * (1.f / 768.f);
  const float var = redB[0] * (1.f / 768.f) - m * m;
  const float is = rsqrtf(var + 1e-5f);
  const float sc = gamma[r] * is;
  const float sh = beta[r] - m * sc;
#pragma unroll
  for (int s = 0; s < 3; ++s) {
    float y = v[s] * sc + sh;
    y = (y >= 0.f) ? y : 0.01f * y;
    h2[r * 768 + t + s * 256] = y;
  }
}

// node MLP layer1: logits[n][r] = bn(n_w1 @ h2)[r][n]  (no lrelu)
__global__ void mlp1_kernel(const float* __restrict__ h2, const float* __restrict__ w,
                            const float* __restrict__ gamma, const float* __restrict__ beta,
                            float* __restrict__ logits)
{
  __shared__ float wr[130];
  __shared__ float redA[256], redB[256];
  const int r = (int)blockIdx.x, t = (int)threadIdx.x;
  if (t < 130) wr[t] = w[r * 130 + t];
  __syncthreads();
  float v[3];
#pragma unroll
  for (int s = 0; s < 3; ++s) {
    const int n = t + s * 256;
    float acc = 0.f;
    for (int c = 0; c < 130; ++c) acc += wr[c] * h2[c * 768 + n];
    v[s] = acc;
  }
  redA[t] = v[0] + v[1] + v[2];
  redB[t] = v[0] * v[0] + v[1] * v[1] + v[2] * v[2];
  __syncthreads();
  for (int off = 128; off > 0; off >>= 1) {
    if (t < off) { redA[t] += redA[t + off]; redB[t] += redB[t + off]; }
    __syncthreads();
  }
  const float m = redA[0] * (1.f / 768.f);
  const float var = redB[0] * (1.f / 768.f) - m * m;
  const float is = rsqrtf(var + 1e-5f);
  const float sc = gamma[r] * is;
  const float sh = beta[r] - m * sc;
#pragma unroll
  for (int s = 0; s < 3; ++s) {
    const float y = v[s] * sc + sh;
    logits[(t + s * 256) * 65 + r] = y;
  }
}

// ---------------------------------------------------------------------------
extern "C" void kernel_launch(void* const* d_in, const int* in_sizes, int n_in,
                              void* d_out, int out_size, void* d_ws, size_t ws_size,
                              hipStream_t stream)
{
  (void)in_sizes; (void)n_in; (void)out_size; (void)ws_size;
  const float* feat   = (const float*)d_in[0];
  const int*   lab    = (const int*)d_in[1];
  const float* e_w0   = (const float*)d_in[2];
  const float* e_g0   = (const float*)d_in[3];
  const float* e_b0   = (const float*)d_in[4];
  const float* e_w1   = (const float*)d_in[5];
  const float* e_g1   = (const float*)d_in[6];
  const float* e_b1   = (const float*)d_in[7];
  const float* e_wout = (const float*)d_in[8];
  const float* e_bout = (const float*)d_in[9];
  const float* n_w0   = (const float*)d_in[10];
  const float* n_g0   = (const float*)d_in[11];
  const float* n_b0   = (const float*)d_in[12];
  const float* n_w1   = (const float*)d_in[13];
  const float* n_g1   = (const float*)d_in[14];
  const float* n_b1   = (const float*)d_in[15];

  float* out = (float*)d_out;
  float* logits = out;                 // 768*65
  float* sim = out + 768 * 65;         // 768*768

  // workspace layout (floats)
  float* wsf = (float*)d_ws;
  float* S0A = wsf + 0;      // 256  (sum z0)
  float* S0B = wsf + 256;    // 256  (sumsq z0)
  float* S1A = wsf + 512;    // 128
  float* S1B = wsf + 640;    // 128
  float* colsum = wsf + 768; // 768
  float* sc0 = wsf + 1536;   // 256
  float* sh0 = wsf + 1792;   // 256
  float* sc1 = wsf + 2048;   // 128
  float* sh1 = wsf + 2176;   // 128
  float* aggr = wsf + 2304;            // 768*128
  float* h2 = wsf + 2304 + 768 * 128;  // 130*768
  unsigned short* W0bf = (unsigned short*)(wsf + 200448);   // 32768 bf16 (64KB)
  unsigned short* W1bf = W0bf + 32768;                      // 32768 bf16 (64KB)

  // zero stat + colsum accumulators (replayed every graph launch)
  hipMemsetAsync(d_ws, 0, 2304 * sizeof(float), stream);

  wcast_kernel<<<128, 256, 0, stream>>>(e_w0, e_w1, W0bf, W1bf);

  pair_phase_kernel<1><<<2304, 512, 0, stream>>>(feat, W0bf, nullptr, nullptr, nullptr,
                                                 nullptr, nullptr, nullptr, nullptr, S0A, nullptr);
  finalize_kernel<<<1, 256, 0, stream>>>(S0A, S0B, e_g0, e_b0, sc0, sh0, 256);
  pair_phase_kernel<2><<<2304, 512, 0, stream>>>(feat, W0bf, W1bf, nullptr, nullptr,
                                                 sc0, sh0, nullptr, nullptr, S1A, nullptr);
  finalize_kernel<<<1, 128, 0, stream>>>(S1A, S1B, e_g1, e_b1, sc1, sh1, 128);
  pair_phase_kernel<3><<<4608, 512, 0, stream>>>(feat, W0bf, W1bf, e_wout, e_bout,
                                                 sc0, sh0, sc1, sh1, nullptr, sim);
  colsum_kernel<<<96, 256, 0, stream>>>(sim, lab, colsum);
  aggr_kernel<<<768, 128, 0, stream>>>(sim, lab, colsum, feat, aggr);
  mlp0_kernel<<<130, 256, 0, stream>>>(feat, aggr, n_w0, n_g0, n_b0, h2);
  mlp1_kernel<<<65, 256, 0, stream>>>(h2, n_w1, n_g1, n_b1, logits);
}

// Round 6
// 662.007 us; speedup vs baseline: 2.1179x; 2.1179x over previous
//
#include <hip/hip_runtime.h>
#include <cmath>

// ---------------------------------------------------------------------------
// ClassifierGNN: N=768 nodes, D=128 feat, edge-MLP channels 256->128->1,
// node-MLP 256->130->65.
// Heavy part: per-pair edge MLP over 768^2 pairs with global BatchNorm.
// 3 recompute phases (stats0, stats1, sim) using bf16 MFMA 16x16x32.
// R5 -> R6: align VGPR budget with working set.
//   Allocator rule (established R1-R5): budget = 512/max(4, LDS-allowed
//   waves/SIMD). R5's 34.8K LDS => 4 blk/CU => 64-reg budget => worse spill.
//   Fix: keep the small 8x8 tile (working set ~75-98 regs) but UN-OVERLAY
//   LDS to 59.4KB => 2 blk/CU => 128-reg budget (verified in R4).
//   No overlay also removes one barrier per tile.
// ---------------------------------------------------------------------------

#define N_NODES 768
#define NBJ 96          // j-tiles per row of tiles (768/8)
#define NTILES 9216     // (768/8) * (768/8)

// LDS layout (bytes), NO overlay: total 59392 -> 2 blocks/CU.
#define L_FEAT 0        // 16 rows * 128 f32 = 8192
#define L_X    8192     // 64 q * 128 c * bf16 = 16384
#define L_A0   24576    // 64 q * 256 c * bf16 = 32768
#define L_SB   57344    // 512 f32 = 2048 (stat/sim staging)
#define L_TOT  59392

static_assert(L_TOT > 53760 && L_TOT <= 81920, "want exactly 2 blocks/CU");

typedef __bf16 bf16x8_t __attribute__((ext_vector_type(8)));
typedef float f32x4_t __attribute__((ext_vector_type(4)));
typedef unsigned short u16x8_t __attribute__((ext_vector_type(8)));
typedef unsigned short u16x4_t __attribute__((ext_vector_type(4)));

__device__ __forceinline__ unsigned short f2bf(float f) {
  unsigned int u = __float_as_uint(f);
  u += 0x7fffu + ((u >> 16) & 1u);          // round-to-nearest-even
  return (unsigned short)(u >> 16);
}

// ---------------------------------------------------------------------------
// Weight pre-cast: f32 -> bf16, same row-major layout (fragment-ready).
// ---------------------------------------------------------------------------
__global__ void wcast_kernel(const float* __restrict__ w0, const float* __restrict__ w1,
                             unsigned short* __restrict__ w0b, unsigned short* __restrict__ w1b)
{
  const int i = (int)(blockIdx.x * 256 + threadIdx.x);
  if (i < 32768) { w0b[i] = f2bf(w0[i]); w1b[i] = f2bf(w1[i]); }
}

// ---------------------------------------------------------------------------
// Fused pair-MLP kernel.
// Tile = 8 i-rows x 8 j-cols = 64 pairs. 512 threads = 8 waves.
// Waves: aog = wid>>1 (layer0: 64 o's / layer1: 32 p's), bqg = wid&1 (32 q's).
// PHASE 1: z0 -> per-channel sum/sumsq (atomics)
// PHASE 2: z0 -> a0 -> z1 -> sum/sumsq
// PHASE 3: z0 -> a0 -> z1 -> a1 -> sim = sigmoid(wout.a1 + bout)
// A-fragments (weights) loaded per-ks from bf16 global (L2-resident).
// ---------------------------------------------------------------------------
template<int PHASE>
__global__ void
__attribute__((amdgpu_flat_work_group_size(512, 512)))
pair_phase_kernel(const float* __restrict__ feat,
                  const unsigned short* __restrict__ W0b,
                  const unsigned short* __restrict__ W1b,
                  const float* __restrict__ wout,
                  const float* __restrict__ boutp,
                  const float* __restrict__ sc0, const float* __restrict__ sh0,
                  const float* __restrict__ sc1, const float* __restrict__ sh1,
                  float* __restrict__ stats,
                  float* __restrict__ sim)
{
  __shared__ __align__(16) unsigned char smem[L_TOT];
  float* featL = (float*)(smem + L_FEAT);
  unsigned char* Xb = smem + L_X;
  unsigned char* Ab = smem + L_A0;
  float* sb = (float*)(smem + L_SB);

  const int tid = (int)threadIdx.x;
  const int wid = tid >> 6;
  const int lane = tid & 63;
  const int lr = lane & 15;
  const int g = lane >> 4;
  const int aog = wid >> 1;   // 0..3
  const int bqg = wid & 1;    // 0..1

  // per-wave weight base pointers (element offsets; +ot*2048 / +pt*4096 later)
  const unsigned short* W0base = W0b + (aog * 64 + lr) * 128 + g * 8;
  const unsigned short* W1base = W1b + (aog * 32 + lr) * 256 + g * 8;

  float s1[4][4], s2v[4][4];   // phase1 accumulators (z0)
  float t1[2][4], t2v[2][4];   // phase2 accumulators (z1)
  if constexpr (PHASE == 1) {
#pragma unroll
    for (int ot = 0; ot < 4; ++ot)
#pragma unroll
      for (int r2 = 0; r2 < 4; ++r2) { s1[ot][r2] = 0.f; s2v[ot][r2] = 0.f; }
  }
  if constexpr (PHASE == 2) {
#pragma unroll
    for (int pt = 0; pt < 2; ++pt)
#pragma unroll
      for (int r2 = 0; r2 < 4; ++r2) { t1[pt][r2] = 0.f; t2v[pt][r2] = 0.f; }
  }

  for (int tile = (int)blockIdx.x; tile < NTILES; tile += (int)gridDim.x) {
    const int ti = tile / NBJ;
    const int i0 = ti * 8;
    const int j0 = (tile - ti * NBJ) * 8;
    __syncthreads();   // prev tile's LDS reads done before overwrite

    // stage 16 feat rows (8 i-rows, 8 j-rows) -> LDS (512 f32x4 items)
    {
      const int rrow = tid >> 5;
      const int c4 = (tid & 31) * 4;
      const int grow = (rrow < 8) ? (i0 + rrow) : (j0 + rrow - 8);
      *(f32x4_t*)(featL + rrow * 128 + c4) = *(const f32x4_t*)(feat + grow * 128 + c4);
    }
    __syncthreads();

    // generate X[q][c] = |f_i[c] - f_j[c]| as bf16, XOR-swizzled rows
    // 64 q * 16 c-groups = 1024 items; 2 iters/thread
#pragma unroll
    for (int it = 0; it < 2; ++it) {
      const int id = tid + it * 512;
      const int q = id >> 4;
      const int c0 = (id & 15) * 8;
      const float* fi = featL + (q >> 3) * 128 + c0;
      const float* fj = featL + (8 + (q & 7)) * 128 + c0;
      u16x8_t xv;
#pragma unroll
      for (int s = 0; s < 8; ++s) xv[s] = f2bf(fabsf(fi[s] - fj[s]));
      const int off = ((q << 8) + (c0 << 1)) ^ ((q & 7) << 4);
      *(u16x8_t*)(Xb + off) = xv;
    }
    __syncthreads();

    // ---- layer 0: z0[o][q] = W0 . X  (o: 4 tiles/wave, q: 2 tiles/wave) ----
    f32x4_t acc0[4][2];
#pragma unroll
    for (int ot = 0; ot < 4; ++ot)
#pragma unroll
      for (int qt = 0; qt < 2; ++qt)
        acc0[ot][qt] = f32x4_t{0.f, 0.f, 0.f, 0.f};
#pragma unroll
    for (int ks = 0; ks < 4; ++ks) {
      bf16x8_t Af[4];
#pragma unroll
      for (int ot = 0; ot < 4; ++ot)
        Af[ot] = *(const bf16x8_t*)(W0base + ot * 2048 + ks * 32);
      bf16x8_t Bf[2];
#pragma unroll
      for (int qt = 0; qt < 2; ++qt) {
        const int q = bqg * 32 + qt * 16 + lr;
        const int off = ((q << 8) + (ks << 6) + (g << 4)) ^ ((q & 7) << 4);
        Bf[qt] = *(const bf16x8_t*)(Xb + off);
      }
      __builtin_amdgcn_sched_barrier(0);   // cap operand window to this iter
#pragma unroll
      for (int ot = 0; ot < 4; ++ot)
#pragma unroll
        for (int qt = 0; qt < 2; ++qt)
          acc0[ot][qt] = __builtin_amdgcn_mfma_f32_16x16x32_bf16(Af[ot], Bf[qt], acc0[ot][qt], 0, 0, 0);
      __builtin_amdgcn_sched_barrier(0);
    }

    if constexpr (PHASE == 1) {
#pragma unroll
      for (int ot = 0; ot < 4; ++ot)
#pragma unroll
        for (int qt = 0; qt < 2; ++qt)
#pragma unroll
          for (int r2 = 0; r2 < 4; ++r2) {
            const float z = acc0[ot][qt][r2];
            s1[ot][r2] += z;
            s2v[ot][r2] += z * z;
          }
    } else {
      // a0 = lrelu(scale0*z0 + shift0), write bf16 into swizzled LDS [q][o]
      // (Ab is a separate region: no hazard with other waves' Xb reads; the
      //  post-write barrier below orders a0 writes vs layer-1 reads.)
#pragma unroll
      for (int ot = 0; ot < 4; ++ot) {
        const int o0 = aog * 64 + ot * 16 + g * 4;
        const f32x4_t scv = *(const f32x4_t*)(sc0 + o0);
        const f32x4_t shv = *(const f32x4_t*)(sh0 + o0);
#pragma unroll
        for (int qt = 0; qt < 2; ++qt) {
          const int q = bqg * 32 + qt * 16 + lr;
          u16x4_t pk;
#pragma unroll
          for (int r2 = 0; r2 < 4; ++r2) {
            float v = acc0[ot][qt][r2] * scv[r2] + shv[r2];
            v = (v >= 0.f) ? v : 0.01f * v;
            pk[r2] = f2bf(v);
          }
          const int off = ((q << 9) + (o0 << 1)) ^ ((q & 7) << 4);
          *(u16x4_t*)(Ab + off) = pk;
        }
      }
      __syncthreads();

      // ---- layer 1: z1[p][q] = W1 . a0 ----
      f32x4_t acc1[2][2];
#pragma unroll
      for (int pt = 0; pt < 2; ++pt)
#pragma unroll
        for (int qt = 0; qt < 2; ++qt)
          acc1[pt][qt] = f32x4_t{0.f, 0.f, 0.f, 0.f};
#pragma unroll
      for (int ks = 0; ks < 8; ++ks) {
        bf16x8_t Af1[2];
#pragma unroll
        for (int pt = 0; pt < 2; ++pt)
          Af1[pt] = *(const bf16x8_t*)(W1base + pt * 4096 + ks * 32);
        bf16x8_t Bf[2];
#pragma unroll
        for (int qt = 0; qt < 2; ++qt) {
          const int q = bqg * 32 + qt * 16 + lr;
          const int off = ((q << 9) + (ks << 6) + (g << 4)) ^ ((q & 7) << 4);
          Bf[qt] = *(const bf16x8_t*)(Ab + off);
        }
        __builtin_amdgcn_sched_barrier(0);
#pragma unroll
        for (int pt = 0; pt < 2; ++pt)
#pragma unroll
          for (int qt = 0; qt < 2; ++qt)
            acc1[pt][qt] = __builtin_amdgcn_mfma_f32_16x16x32_bf16(Af1[pt], Bf[qt], acc1[pt][qt], 0, 0, 0);
        __builtin_amdgcn_sched_barrier(0);
      }

      if constexpr (PHASE == 2) {
#pragma unroll
        for (int pt = 0; pt < 2; ++pt)
#pragma unroll
          for (int qt = 0; qt < 2; ++qt)
#pragma unroll
            for (int r2 = 0; r2 < 4; ++r2) {
              const float z = acc1[pt][qt][r2];
              t1[pt][r2] += z;
              t2v[pt][r2] += z * z;
            }
      } else {
        // PHASE 3: a1 = lrelu(scale1*z1+shift1); sim = sigmoid(wout.a1+bout)
        float part[2] = {0.f, 0.f};
#pragma unroll
        for (int pt = 0; pt < 2; ++pt) {
          const int p0 = aog * 32 + pt * 16 + g * 4;
          const f32x4_t scv = *(const f32x4_t*)(sc1 + p0);
          const f32x4_t shv = *(const f32x4_t*)(sh1 + p0);
          const f32x4_t wv = *(const f32x4_t*)(wout + p0);
#pragma unroll
          for (int qt = 0; qt < 2; ++qt)
#pragma unroll
            for (int r2 = 0; r2 < 4; ++r2) {
              float v = acc1[pt][qt][r2] * scv[r2] + shv[r2];
              v = (v >= 0.f) ? v : 0.01f * v;
              part[qt] += wv[r2] * v;
            }
        }
#pragma unroll
        for (int qt = 0; qt < 2; ++qt) {   // reduce over g (p sub-slots)
          part[qt] += __shfl_xor(part[qt], 16, 64);
          part[qt] += __shfl_xor(part[qt], 32, 64);
        }
        if (lane < 16) {
#pragma unroll
          for (int qt = 0; qt < 2; ++qt)
            sb[aog * 64 + bqg * 32 + qt * 16 + lr] = part[qt];
        }
        __syncthreads();
        if (tid < 64) {
          const float sv = sb[tid] + sb[64 + tid] + sb[128 + tid] + sb[192 + tid] + boutp[0];
          const float sg = 1.f / (1.f + expf(-sv));
          sim[(i0 + (tid >> 3)) * N_NODES + j0 + (tid & 7)] = sg;
        }
      }
    }
  }

  // ---- stats flush: shuffle-reduce over the 16 q-lanes, combine the two
  //      q-group waves in LDS, then one atomicAdd per stat per block. ----
  if constexpr (PHASE == 1) {
#pragma unroll
    for (int ot = 0; ot < 4; ++ot)
#pragma unroll
      for (int r2 = 0; r2 < 4; ++r2) {
        float v1 = s1[ot][r2], v2 = s2v[ot][r2];
#pragma unroll
        for (int m = 1; m < 16; m <<= 1) {
          v1 += __shfl_xor(v1, m, 64);
          v2 += __shfl_xor(v2, m, 64);
        }
        s1[ot][r2] = v1; s2v[ot][r2] = v2;
      }
    __syncthreads();
    if (bqg == 0 && lr == 0) {
#pragma unroll
      for (int ot = 0; ot < 4; ++ot)
#pragma unroll
        for (int r2 = 0; r2 < 4; ++r2) {
          const int o = aog * 64 + ot * 16 + g * 4 + r2;
          sb[o] = s1[ot][r2];
          sb[256 + o] = s2v[ot][r2];
        }
    }
    __syncthreads();
    if (bqg == 1 && lr == 0) {
#pragma unroll
      for (int ot = 0; ot < 4; ++ot)
#pragma unroll
        for (int r2 = 0; r2 < 4; ++r2) {
          const int o = aog * 64 + ot * 16 + g * 4 + r2;
          sb[o] += s1[ot][r2];
          sb[256 + o] += s2v[ot][r2];
        }
    }
    __syncthreads();
    atomicAdd(stats + tid, sb[tid]);   // tid < 512: 256 sums + 256 sumsq
  }
  if constexpr (PHASE == 2) {
#pragma unroll
    for (int pt = 0; pt < 2; ++pt)
#pragma unroll
      for (int r2 = 0; r2 < 4; ++r2) {
        float v1 = t1[pt][r2], v2 = t2v[pt][r2];
#pragma unroll
        for (int m = 1; m < 16; m <<= 1) {
          v1 += __shfl_xor(v1, m, 64);
          v2 += __shfl_xor(v2, m, 64);
        }
        t1[pt][r2] = v1; t2v[pt][r2] = v2;
      }
    __syncthreads();
    if (bqg == 0 && lr == 0) {
#pragma unroll
      for (int pt = 0; pt < 2; ++pt)
#pragma unroll
        for (int r2 = 0; r2 < 4; ++r2) {
          const int p = aog * 32 + pt * 16 + g * 4 + r2;
          sb[p] = t1[pt][r2];
          sb[128 + p] = t2v[pt][r2];
        }
    }
    __syncthreads();
    if (bqg == 1 && lr == 0) {
#pragma unroll
      for (int pt = 0; pt < 2; ++pt)
#pragma unroll
        for (int r2 = 0; r2 < 4; ++r2) {
          const int p = aog * 32 + pt * 16 + g * 4 + r2;
          sb[p] += t1[pt][r2];
          sb[128 + p] += t2v[pt][r2];
        }
    }
    __syncthreads();
    if (tid < 256) atomicAdd(stats + tid, sb[tid]);
  }
}

// ---------------------------------------------------------------------------
// finalize: mean/var -> per-channel scale/shift for BN(+gamma,beta)
// ---------------------------------------------------------------------------
__global__ void finalize_kernel(const float* __restrict__ ssum, const float* __restrict__ ssq,
                                const float* __restrict__ gamma, const float* __restrict__ beta,
                                float* __restrict__ sc, float* __restrict__ sh, int n)
{
  const int i = (int)(blockIdx.x * blockDim.x + threadIdx.x);
  if (i < n) {
    const float invN = 1.f / 589824.f;
    const float m = ssum[i] * invN;
    const float var = ssq[i] * invN - m * m;
    const float is = rsqrtf(var + 1e-5f);
    const float s = gamma[i] * is;
    sc[i] = s;
    sh[i] = beta[i] - m * s;
  }
}

// ---------------------------------------------------------------------------
// edge graph tail: colsum of edge matrix (edge = same_label*sim + I + 1e-6)
// ---------------------------------------------------------------------------
__global__ void colsum_kernel(const float* __restrict__ sim, const int* __restrict__ lab,
                              float* __restrict__ colsum)
{
  const int t = (int)threadIdx.x;
  const int bi = (int)blockIdx.x * 8;
  const int lj0 = lab[t], lj1 = lab[t + 256], lj2 = lab[t + 512];
  float a0 = 0.f, a1 = 0.f, a2 = 0.f;
  for (int r = 0; r < 8; ++r) {
    const int i = bi + r;
    const int li = lab[i];
    const float* srow = sim + i * N_NODES;
    a0 += ((li == lj0) ? srow[t] : 0.f) + ((i == t) ? 1.f : 0.f) + 1e-6f;
    a1 += ((li == lj1) ? srow[t + 256] : 0.f) + ((i == t + 256) ? 1.f : 0.f) + 1e-6f;
    a2 += ((li == lj2) ? srow[t + 512] : 0.f) + ((i == t + 512) ? 1.f : 0.f) + 1e-6f;
  }
  atomicAdd(colsum + t, a0);
  atomicAdd(colsum + t + 256, a1);
  atomicAdd(colsum + t + 512, a2);
}

// aggr[i][:] = (e_row_i / max(sum|e_row_i|,1e-12)) @ feat,  e = colnorm(edge) with zero diag
__global__ void aggr_kernel(const float* __restrict__ sim, const int* __restrict__ lab,
                            const float* __restrict__ colsum, const float* __restrict__ feat,
                            float* __restrict__ aggr)
{
  __shared__ float wrow[N_NODES];
  __shared__ float red[128];
  const int i = (int)blockIdx.x, t = (int)threadIdx.x;
  const int li = lab[i];
  const float* srow = sim + i * N_NODES;
  float rs = 0.f;
  for (int s = 0; s < 6; ++s) {
    const int j = t + s * 128;
    const float e = ((li == lab[j]) ? srow[j] : 0.f) + ((i == j) ? 1.f : 0.f) + 1e-6f;
    const float w = (j == i) ? 0.f : e / colsum[j];
    wrow[j] = w;
    rs += w;
  }
  red[t] = rs;
  __syncthreads();
  for (int off = 64; off > 0; off >>= 1) {
    if (t < off) red[t] += red[t + off];
    __syncthreads();
  }
  const float inv = 1.f / fmaxf(red[0], 1e-12f);
  float acc = 0.f;
  for (int j = 0; j < N_NODES; ++j) acc += wrow[j] * feat[j * 128 + t];
  aggr[i * 128 + t] = acc * inv;
}

// node MLP layer0: h2[r][n] = lrelu(bn(n_w0 @ [feat;aggr]^T)), bn over n
__global__ void mlp0_kernel(const float* __restrict__ feat, const float* __restrict__ aggr,
                            const float* __restrict__ w, const float* __restrict__ gamma,
                            const float* __restrict__ beta, float* __restrict__ h2)
{
  __shared__ float wr[256];
  __shared__ float redA[256], redB[256];
  const int r = (int)blockIdx.x, t = (int)threadIdx.x;
  wr[t] = w[r * 256 + t];
  __syncthreads();
  float v[3];
#pragma unroll
  for (int s = 0; s < 3; ++s) {
    const int n = t + s * 256;
    const float* fr = feat + n * 128;
    const float* ar = aggr + n * 128;
    float acc = 0.f;
#pragma unroll 4
    for (int c = 0; c < 128; c += 4) {
      const f32x4_t fv = *(const f32x4_t*)(fr + c);
      acc += wr[c] * fv[0] + wr[c + 1] * fv[1] + wr[c + 2] * fv[2] + wr[c + 3] * fv[3];
    }
#pragma unroll 4
    for (int c = 0; c < 128; c += 4) {
      const f32x4_t av = *(const f32x4_t*)(ar + c);
      acc += wr[128 + c] * av[0] + wr[129 + c] * av[1] + wr[130 + c] * av[2] + wr[131 + c] * av[3];
    }
    v[s] = acc;
  }
  redA[t] = v[0] + v[1] + v[2];
  redB[t] = v[0] * v[0] + v[1] * v[1] + v[2] * v[2];
  __syncthreads();
  for (int off = 128; off > 0; off >>= 1) {
    if (t < off) { redA[t] += redA[t + off]; redB[t] += redB[t + off]; }
    __syncthreads();
  }
  const float m = redA[0] * (1.f / 768.f);
  const float var = redB[0] * (1.f / 768.f) - m * m;
  const float is = rsqrtf(var + 1e-5f);
  const float sc = gamma[r] * is;
  const float sh = beta[r] - m * sc;
#pragma unroll
  for (int s = 0; s < 3; ++s) {
    float y = v[s] * sc + sh;
    y = (y >= 0.f) ? y : 0.01f * y;
    h2[r * 768 + t + s * 256] = y;
  }
}

// node MLP layer1: logits[n][r] = bn(n_w1 @ h2)[r][n]  (no lrelu)
__global__ void mlp1_kernel(const float* __restrict__ h2, const float* __restrict__ w,
                            const float* __restrict__ gamma, const float* __restrict__ beta,
                            float* __restrict__ logits)
{
  __shared__ float wr[130];
  __shared__ float redA[256], redB[256];
  const int r = (int)blockIdx.x, t = (int)threadIdx.x;
  if (t < 130) wr[t] = w[r * 130 + t];
  __syncthreads();
  float v[3];
#pragma unroll
  for (int s = 0; s < 3; ++s) {
    const int n = t + s * 256;
    float acc = 0.f;
    for (int c = 0; c < 130; ++c) acc += wr[c] * h2[c * 768 + n];
    v[s] = acc;
  }
  redA[t] = v[0] + v[1] + v[2];
  redB[t] = v[0] * v[0] + v[1] * v[1] + v[2] * v[2];
  __syncthreads();
  for (int off = 128; off > 0; off >>= 1) {
    if (t < off) { redA[t] += redA[t + off]; redB[t] += redB[t + off]; }
    __syncthreads();
  }
  const float m = redA[0] * (1.f / 768.f);
  const float var = redB[0] * (1.f / 768.f) - m * m;
  const float is = rsqrtf(var + 1e-5f);
  const float sc = gamma[r] * is;
  const float sh = beta[r] - m * sc;
#pragma unroll
  for (int s = 0; s < 3; ++s) {
    const float y = v[s] * sc + sh;
    logits[(t + s * 256) * 65 + r] = y;
  }
}

// ---------------------------------------------------------------------------
extern "C" void kernel_launch(void* const* d_in, const int* in_sizes, int n_in,
                              void* d_out, int out_size, void* d_ws, size_t ws_size,
                              hipStream_t stream)
{
  (void)in_sizes; (void)n_in; (void)out_size; (void)ws_size;
  const float* feat   = (const float*)d_in[0];
  const int*   lab    = (const int*)d_in[1];
  const float* e_w0   = (const float*)d_in[2];
  const float* e_g0   = (const float*)d_in[3];
  const float* e_b0   = (const float*)d_in[4];
  const float* e_w1   = (const float*)d_in[5];
  const float* e_g1   = (const float*)d_in[6];
  const float* e_b1   = (const float*)d_in[7];
  const float* e_wout = (const float*)d_in[8];
  const float* e_bout = (const float*)d_in[9];
  const float* n_w0   = (const float*)d_in[10];
  const float* n_g0   = (const float*)d_in[11];
  const float* n_b0   = (const float*)d_in[12];
  const float* n_w1   = (const float*)d_in[13];
  const float* n_g1   = (const float*)d_in[14];
  const float* n_b1   = (const float*)d_in[15];

  float* out = (float*)d_out;
  float* logits = out;                 // 768*65
  float* sim = out + 768 * 65;         // 768*768

  // workspace layout (floats)
  float* wsf = (float*)d_ws;
  float* S0A = wsf + 0;      // 256  (sum z0)
  float* S0B = wsf + 256;    // 256  (sumsq z0)
  float* S1A = wsf + 512;    // 128
  float* S1B = wsf + 640;    // 128
  float* colsum = wsf + 768; // 768
  float* sc0 = wsf + 1536;   // 256
  float* sh0 = wsf + 1792;   // 256
  float* sc1 = wsf + 2048;   // 128
  float* sh1 = wsf + 2176;   // 128
  float* aggr = wsf + 2304;            // 768*128
  float* h2 = wsf + 2304 + 768 * 128;  // 130*768
  unsigned short* W0bf = (unsigned short*)(wsf + 200448);   // 32768 bf16 (64KB)
  unsigned short* W1bf = W0bf + 32768;                      // 32768 bf16 (64KB)

  // zero stat + colsum accumulators (replayed every graph launch)
  hipMemsetAsync(d_ws, 0, 2304 * sizeof(float), stream);

  wcast_kernel<<<128, 256, 0, stream>>>(e_w0, e_w1, W0bf, W1bf);

  pair_phase_kernel<1><<<2304, 512, 0, stream>>>(feat, W0bf, nullptr, nullptr, nullptr,
                                                 nullptr, nullptr, nullptr, nullptr, S0A, nullptr);
  finalize_kernel<<<1, 256, 0, stream>>>(S0A, S0B, e_g0, e_b0, sc0, sh0, 256);
  pair_phase_kernel<2><<<2304, 512, 0, stream>>>(feat, W0bf, W1bf, nullptr, nullptr,
                                                 sc0, sh0, nullptr, nullptr, S1A, nullptr);
  finalize_kernel<<<1, 128, 0, stream>>>(S1A, S1B, e_g1, e_b1, sc1, sh1, 128);
  pair_phase_kernel<3><<<4608, 512, 0, stream>>>(feat, W0bf, W1bf, e_wout, e_bout,
                                                 sc0, sh0, sc1, sh1, nullptr, sim);
  colsum_kernel<<<96, 256, 0, stream>>>(sim, lab, colsum);
  aggr_kernel<<<768, 128, 0, stream>>>(sim, lab, colsum, feat, aggr);
  mlp0_kernel<<<130, 256, 0, stream>>>(feat, aggr, n_w0, n_g0, n_b0, h2);
  mlp1_kernel<<<65, 256, 0, stream>>>(h2, n_w1, n_g1, n_b1, logits);
}